// Round 1
// baseline (499.049 us; speedup 1.0000x reference)
//
#include <hip/hip_runtime.h>

// Problem constants (fixed by setup_inputs).
#define N_SAMP 80
#define C_CH   2048
#define HW     256          // 16*16
#define S_TOP  512
#define HW4    64           // HW / 4 (float4 per channel)

// ---------------------------------------------------------------------------
// Kernel 1: per-row top-512 via full bitonic sort of 2048 packed keys.
// key = (monotone float bits << 11) | (2047 - idx)
//   - descending sort => score desc primary, index asc tie-break (matches
//     jax.lax.top_k's "lower index first on ties").
// Writes inverted rank map: rank[n][ch] = k in [0,512) or -1.
// ---------------------------------------------------------------------------
__global__ __launch_bounds__(256) void topk_rank_kernel(
    const float* __restrict__ s_ca, int* __restrict__ rank) {
  __shared__ unsigned long long keys[C_CH];
  const int n = blockIdx.x;
  const int tid = threadIdx.x;
  const float* row = s_ca + (size_t)n * C_CH;

  for (int i = tid; i < C_CH; i += 256) {
    unsigned int b = __float_as_uint(row[i]);
    // monotone transform: order of uint == order of float (handles negatives)
    b ^= (b & 0x80000000u) ? 0xFFFFFFFFu : 0x80000000u;
    keys[i] = ((unsigned long long)b << 11) |
              (unsigned long long)(C_CH - 1 - i);
  }
  __syncthreads();

  // Bitonic sort, descending.
  for (int k = 2; k <= C_CH; k <<= 1) {
    for (int j = k >> 1; j > 0; j >>= 1) {
      for (int t = tid; t < C_CH / 2; t += 256) {
        int i = ((t & ~(j - 1)) << 1) | (t & (j - 1));  // bit j of i is 0
        int ixj = i | j;
        bool desc = ((i & k) == 0);
        unsigned long long a = keys[i];
        unsigned long long c2 = keys[ixj];
        if ((a < c2) == desc) {
          keys[i] = c2;
          keys[ixj] = a;
        }
      }
      __syncthreads();
    }
  }

  int* rrow = rank + (size_t)n * C_CH;
  for (int i = tid; i < C_CH; i += 256) rrow[i] = -1;
  __syncthreads();
  for (int t = tid; t < S_TOP; t += 256) {
    int idx = (C_CH - 1) - (int)(keys[t] & 2047ULL);
    rrow[idx] = t;
  }
}

// ---------------------------------------------------------------------------
// Kernel 2: produce output. One float4 (16B) per thread.
// out[m, ch, hw] with m = g*32 + b; n = g*16 + (b&15); aug = (b>=16).
//   plain: x[n,ch,:] * s[n,ch]
//   aug  : ch in topk(n) at rank k ?
//          (0.7*x[n,ch,:] + 0.3*x[j(n), rand_index[n,k], :]) * s : x*s
// ---------------------------------------------------------------------------
__global__ __launch_bounds__(256) void shuffle_out_kernel(
    const float4* __restrict__ x4, const float* __restrict__ s_ca,
    const int* __restrict__ rand_index, const int* __restrict__ partner,
    const int* __restrict__ rank, float4* __restrict__ out4) {
  const unsigned int p = blockIdx.x * 256u + threadIdx.x;  // float4 index
  const unsigned int m = p >> 17;            // / (2048*64)
  const unsigned int r = p & 131071u;
  const unsigned int ch = r >> 6;
  const unsigned int q = r & 63u;            // float4 within channel

  const unsigned int b = m & 31u;
  const unsigned int n = ((m >> 5) << 4) | (b & 15u);  // g*16 + (b&15)
  const bool aug = (b >= 16u);

  const float s = s_ca[(size_t)n * C_CH + ch];
  float4 v = x4[((size_t)n * C_CH + ch) * HW4 + q];

  if (aug) {
    const int k = rank[(size_t)n * C_CH + ch];
    if (k >= 0) {
      int jn = (int)n + 1 + partner[n];
      if (jn >= N_SAMP) jn -= N_SAMP;
      const int pc = rand_index[(size_t)n * S_TOP + k];
      const float4 u = x4[((size_t)jn * C_CH + pc) * HW4 + q];
      v.x = 0.7f * v.x + 0.3f * u.x;
      v.y = 0.7f * v.y + 0.3f * u.y;
      v.z = 0.7f * v.z + 0.3f * u.z;
      v.w = 0.7f * v.w + 0.3f * u.w;
    }
  }

  v.x *= s; v.y *= s; v.z *= s; v.w *= s;
  out4[p] = v;
}

extern "C" void kernel_launch(void* const* d_in, const int* in_sizes, int n_in,
                              void* d_out, int out_size, void* d_ws,
                              size_t ws_size, hipStream_t stream) {
  const float* x = (const float*)d_in[0];
  const float* s_ca = (const float*)d_in[1];
  const int* rand_index = (const int*)d_in[2];
  const int* partner = (const int*)d_in[3];
  // d_in[4] = shuffle_num (512, fixed by setup)

  int* rank = (int*)d_ws;  // N_SAMP * C_CH ints = 655,360 B

  topk_rank_kernel<<<N_SAMP, 256, 0, stream>>>(s_ca, rank);

  // out float4 count = 160 * 2048 * 64 = 20,971,520 = 81920 blocks * 256 thr
  const int nblocks = (2 * N_SAMP * C_CH * HW4) / 256;
  shuffle_out_kernel<<<nblocks, 256, 0, stream>>>(
      (const float4*)x, s_ca, rand_index, partner, rank, (float4*)d_out);
}